// Round 8
// baseline (679.424 us; speedup 1.0000x reference)
//
#include <hip/hip_runtime.h>
#include <stdint.h>

#define M_TOK 4096
#define K_IN  4096
#define N_OUT 11008
#define GROUPS 64
#define WPR 512            // packed words per weight row = K_IN/8

// ---- 256x256 8-phase GEMM geometry ----
#define BM 256
#define BN 256
#define BK 64
#define TM (M_TOK / BM)    // 16
#define TN (N_OUT / BN)    // 43
#define NWG (TM * TN)      // 688
#define KTILES (K_IN / BK) // 64

typedef __bf16 bf16x8 __attribute__((ext_vector_type(8)));
typedef float  f32x4  __attribute__((ext_vector_type(4)));

__device__ __forceinline__ uint16_t f2bf(float f) {
  uint32_t u = __float_as_uint(f);
  u += 0x7FFFu + ((u >> 16) & 1u);
  return (uint16_t)(u >> 16);
}

// ---------------------------------------------------------------------------
// Round 8: W-prep is GONE. prep converts x only; the gemm dequants int4 B
// inline during staging. Saves wb write+read (2x86 MB) + the entire prep-W
// kernel time, and cuts gemm FETCH by ~500 MB.
// ---------------------------------------------------------------------------
#define XBLK ((M_TOK * K_IN) / (256 * 8))        // 8192

__global__ __launch_bounds__(256) void prep_x(const float* __restrict__ x,
                                              uint16_t* __restrict__ xb) {
  size_t i = ((size_t)blockIdx.x * 256 + threadIdx.x) * 8;
  const float4* p = (const float4*)(x + i);
  float4 a = p[0];
  float4 b = p[1];
  uint4 v;
  v.x = (uint32_t)f2bf(a.x) | ((uint32_t)f2bf(a.y) << 16);
  v.y = (uint32_t)f2bf(a.z) | ((uint32_t)f2bf(a.w) << 16);
  v.z = (uint32_t)f2bf(b.x) | ((uint32_t)f2bf(b.y) << 16);
  v.w = (uint32_t)f2bf(b.z) | ((uint32_t)f2bf(b.w) << 16);
  *(uint4*)(xb + i) = v;
}

// ---------------------------------------------------------------------------
// 256x256x64 8-phase GEMM with fused B-dequant (round 8).
//
// B staging (replaces gload_lds): per B-stage each thread covers rows
// r0 = half*128 + wave*8 + lrow and r0+64, chunk lcol (8 bf16 = 4 B packed).
//   ISSUE_B @ phase p-2: 2x qw dword + 2x qz + 2x sc  (plain reg loads)
//   DEQ_B   @ phase p  : implicit vmcnt wait, dequant 16 weights,
//                        2x ds_write_b128 to LDS[r][lcol^lrow]  (same
//                        swizzle identity as before: LDS[row][c] holds
//                        global chunk c^(row&7); read path unchanged).
//   Bank audit: rows are 128 B apart (bank-aligned); per row-group the 8
//   chunks cover all 32 banks once -> conflict-free b128 writes.
//
// vmcnt ledger (NO explicit waits needed in the loop):
//   issues: A gload_lds @ ph1,2,5,6; B reg-batches @ ph1(->3), 2(->4),
//           5(->7), 6(->next 0). Source order per phase: A first, then B.
//   Each DEQ's implicit wait (batch issued at p-2) cascade-retires every
//   older vmem op, so each A stage is complete 2 phases after issue:
//     A@ph1 retired ph3 (read ph6) / A@ph2 ph4 (next ph0) /
//     A@ph5 ph7 (next ph2) / A@ph6 next-ph0 (next ph4).  All safe.
//   B write-overwrite ledger (write at p vs region's last frag-read):
//     b1.Bh0 w@0 r@prev4 | b0.Bh1 w@3 r@1 | b0.Bh0 w@4 r@0 | b1.Bh1 w@7 r@5.
//   A stage targets identical to r7 (unchanged gload path).
// Consume order per K-tile: M0N0, M0N1, M1N1, M1N0; B frags persistent (r7).
// ---------------------------------------------------------------------------
#define SBAR()   __builtin_amdgcn_s_barrier()
#define SCHED0() __builtin_amdgcn_sched_barrier(0)
#define WAITV(n) asm volatile("s_waitcnt vmcnt(" #n ")" ::: "memory")

struct BB { uint32_t w0, w1, z0, z1; float s0, s1; };

__device__ __forceinline__ uint4 deq8(uint32_t w, float s, float c) {
  union { __bf16 h[8]; uint4 v; } u;
#pragma unroll
  for (int j = 0; j < 8; j++)
    u.h[j] = (__bf16)fmaf((float)((w >> (4 * j)) & 15u), s, c);  // RNE cvt == f2bf
  return u.v;
}

#define ISSUE_B(bb, half, kt) do {                                             \
  const int r0_ = (half) * 128 + wave * 8 + lrow;                              \
  const size_t o0_ = n0 + r0_, o1_ = o0_ + 64;                                 \
  bb.w0 = qw[o0_ * WPR + (size_t)(kt) * 8 + lcol];                             \
  bb.w1 = qw[o1_ * WPR + (size_t)(kt) * 8 + lcol];                             \
  bb.z0 = qz[o0_ * (GROUPS / 8) + ((kt) >> 3)];                                \
  bb.z1 = qz[o1_ * (GROUPS / 8) + ((kt) >> 3)];                                \
  bb.s0 = sc[o0_ * GROUPS + (kt)];                                             \
  bb.s1 = sc[o1_ * GROUPS + (kt)];                                             \
} while (0)

#define DEQ_B(buf, half, bb, kt) do {                                          \
  const int r0_ = (half) * 128 + wave * 8 + lrow;                              \
  const float zp0_ = (float)((bb.z0 >> (((kt) & 7) * 4)) & 15u);               \
  const float zp1_ = (float)((bb.z1 >> (((kt) & 7) * 4)) & 15u);               \
  *(uint4*)&Bs[(buf)][r0_][bslot] = deq8(bb.w0, bb.s0, -bb.s0 * zp0_);         \
  *(uint4*)&Bs[(buf)][r0_ + 64][bslot] = deq8(bb.w1, bb.s1, -bb.s1 * zp1_);    \
} while (0)

#define STAGE_A(buf, half, kt) do {                                            \
  _Pragma("unroll")                                                            \
  for (int c_ = 0; c_ < 2; c_++) {                                             \
    const int r_ = (half) * 128 + c_ * 64 + wave * 8;                          \
    __builtin_amdgcn_global_load_lds(                                          \
        (const __attribute__((address_space(1))) uint32_t*)(                   \
            gA + (size_t)r_ * K_IN + (size_t)(kt) * BK),                       \
        (__attribute__((address_space(3))) uint32_t*)(&As[(buf)][r_][0]),      \
        16, 0, 0);                                                             \
  } } while (0)

#define LOAD_A(buf, mh) do {                                                   \
  _Pragma("unroll")                                                            \
  for (int i2_ = 0; i2_ < 4; i2_++) {                                          \
    const int row_ = (mh) * 128 + wm * 64 + i2_ * 16 + col;                    \
    af[i2_][0] = *(const bf16x8*)&As[(buf)][row_][(quad ^ cs) << 3];           \
    af[i2_][1] = *(const bf16x8*)&As[(buf)][row_][((4 + quad) ^ cs) << 3];     \
  } } while (0)

#define LDB_FRAG(buf, nh) do {                                                 \
  _Pragma("unroll")                                                            \
  for (int j2_ = 0; j2_ < 2; j2_++) {                                          \
    const int row_ = (nh) * 128 + wn * 32 + j2_ * 16 + col;                    \
    bfr[(nh)][j2_][0] = *(const bf16x8*)&Bs[(buf)][row_][(quad ^ cs) << 3];    \
    bfr[(nh)][j2_][1] = *(const bf16x8*)&Bs[(buf)][row_][((4 + quad) ^ cs) << 3]; \
  } } while (0)

#define MMA(mh, nh) do {                                                       \
  __builtin_amdgcn_s_setprio(1);                                               \
  _Pragma("unroll")                                                            \
  for (int i2_ = 0; i2_ < 4; i2_++)                                            \
    _Pragma("unroll")                                                          \
    for (int j2_ = 0; j2_ < 2; j2_++) {                                        \
      acc[(mh)*4 + i2_][(nh)*2 + j2_] = __builtin_amdgcn_mfma_f32_16x16x32_bf16( \
          af[i2_][0], bfr[(nh)][j2_][0], acc[(mh)*4 + i2_][(nh)*2 + j2_], 0, 0, 0); \
      acc[(mh)*4 + i2_][(nh)*2 + j2_] = __builtin_amdgcn_mfma_f32_16x16x32_bf16( \
          af[i2_][1], bfr[(nh)][j2_][1], acc[(mh)*4 + i2_][(nh)*2 + j2_], 0, 0, 0); \
    }                                                                          \
  __builtin_amdgcn_s_setprio(0); } while (0)

__global__ __launch_bounds__(512, 2) void gemm_fused(const uint16_t* __restrict__ A,
                                                     const uint32_t* __restrict__ qw,
                                                     const uint32_t* __restrict__ qz,
                                                     const float* __restrict__ sc,
                                                     const float* __restrict__ bias,
                                                     float* __restrict__ C) {
  __shared__ __align__(16) uint16_t As[2][BM][BK];   // 64 KiB
  __shared__ __align__(16) uint16_t Bs[2][BN][BK];   // 64 KiB

  const int bid = blockIdx.x;
  const int wg  = (bid & 7) * (NWG / 8) + (bid >> 3);
  const int mt  = wg / TN;
  const int nt  = wg % TN;
  const size_t m0 = (size_t)mt * BM;
  const size_t n0 = (size_t)nt * BN;

  const int tid  = threadIdx.x;
  const int wave = tid >> 6;
  const int lane = tid & 63;
  const int wm   = wave >> 2;          // 0..1
  const int wn   = wave & 3;           // 0..3
  const int lrow = lane >> 3;          // 0..7
  const int lcol = lane & 7;           // 0..7
  const int col  = lane & 15;
  const int quad = lane >> 4;
  const int cs   = col & 7;
  const int bslot = (lcol ^ lrow) << 3;   // B ds_write slot (uint16 units)

  const uint16_t* gA = A + (m0 + lrow) * K_IN + (size_t)((lcol ^ lrow) << 3);

  f32x4 acc[8][4];
#pragma unroll
  for (int i = 0; i < 8; i++)
#pragma unroll
    for (int j = 0; j < 4; j++)
      acc[i][j] = (f32x4){0.f, 0.f, 0.f, 0.f};

  bf16x8 af[4][2];
  bf16x8 bfr[2][2][2];
  BB bb0, bb1, p0, p1;

  // ---- prologue: A gloads for b0.{h0,h1} + b1.h0; B buf0 both halves and
  // b1.Bh1 dequanted directly; bb0 pre-issued for ph0 (b1.Bh0 <- kt1).
  // DEQ implicit waits cascade-retire all A gloads before the barrier.
  STAGE_A(0, 0, 0); STAGE_A(0, 1, 0); STAGE_A(1, 0, 1);
  ISSUE_B(p0, 0, 0); ISSUE_B(p1, 1, 0);
  DEQ_B(0, 0, p0, 0); DEQ_B(0, 1, p1, 0);
  ISSUE_B(p0, 1, 1);
  DEQ_B(1, 1, p0, 1);
  ISSUE_B(bb0, 0, 1);
  SBAR();

  for (int it = 0; it < KTILES / 2 - 1; ++it) {
    const int kt = 2 * it;
    // ph0: buf0 M0N0 ; write b1.Bh0<-kt+1 (batch from prev ph6 / prologue)
    DEQ_B(1, 0, bb0, kt + 1);
    LOAD_A(0, 0); LDB_FRAG(0, 0);
    MMA(0, 0);
    SBAR();
    // ph1: M0N1 ; stage b1.Ah1<-kt+1 ; issue B batch for ph3
    STAGE_A(1, 1, kt + 1);
    ISSUE_B(bb1, 1, kt + 2); SCHED0();
    LDB_FRAG(0, 1);
    MMA(0, 1);
    SBAR();
    // ph2: M1N1 ; stage b0.Ah0<-kt+2 ; issue B batch for ph4
    STAGE_A(0, 0, kt + 2);
    ISSUE_B(bb0, 0, kt + 2); SCHED0();
    LOAD_A(0, 1);
    MMA(1, 1);
    SBAR();
    // ph3: M1N0 ; write b0.Bh1<-kt+2
    DEQ_B(0, 1, bb1, kt + 2);
    MMA(1, 0);
    SBAR();
    // ph4: buf1 M0N0 ; write b0.Bh0<-kt+2
    DEQ_B(0, 0, bb0, kt + 2);
    LOAD_A(1, 0); LDB_FRAG(1, 0);
    MMA(0, 0);
    SBAR();
    // ph5: M0N1 ; stage b0.Ah1<-kt+2 ; issue B batch for ph7
    STAGE_A(0, 1, kt + 2);
    ISSUE_B(bb1, 1, kt + 3); SCHED0();
    LDB_FRAG(1, 1);
    MMA(0, 1);
    SBAR();
    // ph6: M1N1 ; stage b1.Ah0<-kt+3 ; issue B batch for next ph0
    STAGE_A(1, 0, kt + 3);
    ISSUE_B(bb0, 0, kt + 3); SCHED0();
    LOAD_A(1, 1);
    MMA(1, 1);
    SBAR();
    // ph7: M1N0 ; write b1.Bh1<-kt+3
    DEQ_B(1, 1, bb1, kt + 3);
    MMA(1, 0);
    SBAR();
  }

  // ---- epilogue: kt = 62 (buf0), 63 (buf1).
  DEQ_B(1, 0, bb0, KTILES - 1);           // b1.Bh0 <- 63 (batch from ph6)
  LOAD_A(0, 0); LDB_FRAG(0, 0);
  MMA(0, 0);
  SBAR();
  STAGE_A(1, 1, KTILES - 1);
  LDB_FRAG(0, 1);
  MMA(0, 1);
  SBAR();
  LOAD_A(0, 1);
  MMA(1, 1);
  SBAR();
  MMA(1, 0);
  WAITV(0);                               // retire A@e1 (b1.Ah1) before e4
  SBAR();
  LOAD_A(1, 0); LDB_FRAG(1, 0);
  MMA(0, 0);
  SBAR();
  LDB_FRAG(1, 1);
  MMA(0, 1);
  SBAR();
  LOAD_A(1, 1);
  MMA(1, 1);
  SBAR();
  MMA(1, 0);

  // ---- C write: D row = quad*4 + r, col = lane&15 within each 16x16 frag
#pragma unroll
  for (int i = 0; i < 8; i++) {
    const int mrow = (int)m0 + (i >> 2) * 128 + wm * 64 + (i & 3) * 16 + quad * 4;
#pragma unroll
    for (int j = 0; j < 4; j++) {
      const int ncol = (int)n0 + (j >> 1) * 128 + wn * 32 + (j & 1) * 16 + col;
      const float bv = bias[ncol];
      float* out = C + (size_t)mrow * N_OUT + ncol;
#pragma unroll
      for (int r = 0; r < 4; r++)
        __builtin_nontemporal_store(acc[i][j][r] + bv, out + (size_t)r * N_OUT);
    }
  }
}

// ---------------------------------------------------------------------------
// Fallback (ws too small): correct but slow fused kernel.
// ---------------------------------------------------------------------------
__global__ __launch_bounds__(256) void fallback_fused(const float* __restrict__ x,
                                                      const uint32_t* __restrict__ qw,
                                                      const uint32_t* __restrict__ qz,
                                                      const float* __restrict__ sc,
                                                      const float* __restrict__ bias,
                                                      float* __restrict__ out) {
  __shared__ float xs[K_IN];
  const int t = blockIdx.y;
  const int o = blockIdx.x * 256 + threadIdx.x;
  for (int i = threadIdx.x; i < K_IN; i += 256) xs[i] = x[(size_t)t * K_IN + i];
  __syncthreads();
  float acc = 0.f;
  const uint32_t* qwr = qw + (size_t)o * WPR;
  for (int g = 0; g < GROUPS; g++) {
    uint32_t zw = qz[o * (GROUPS / 8) + (g >> 3)];
    float zp = (float)((zw >> ((g & 7) * 4)) & 15u);
    float s = sc[o * GROUPS + g];
    float gacc = 0.f, gsum = 0.f;
    for (int w = 0; w < 8; w++) {
      uint32_t wv = qwr[g * 8 + w];
#pragma unroll
      for (int j = 0; j < 8; j++) {
        float xv = xs[g * 64 + w * 8 + j];
        gacc = fmaf((float)((wv >> (4 * j)) & 15u), xv, gacc);
        gsum += xv;
      }
    }
    acc += s * (gacc - zp * gsum);
  }
  out[(size_t)t * N_OUT + o] = acc + bias[o];
}

// ---------------------------------------------------------------------------
extern "C" void kernel_launch(void* const* d_in, const int* in_sizes, int n_in,
                              void* d_out, int out_size, void* d_ws, size_t ws_size,
                              hipStream_t stream) {
  (void)in_sizes; (void)n_in; (void)out_size;
  const float*    x    = (const float*)d_in[0];
  const uint32_t* qw   = (const uint32_t*)d_in[1];
  const uint32_t* qz   = (const uint32_t*)d_in[2];
  const float*    sc   = (const float*)d_in[3];
  const float*    bias = (const float*)d_in[4];
  float* out = (float*)d_out;

  const size_t xb_bytes = (size_t)M_TOK * K_IN * 2;

  if (ws_size >= xb_bytes) {
    uint16_t* xb = (uint16_t*)d_ws;
    prep_x<<<XBLK, 256, 0, stream>>>(x, xb);
    gemm_fused<<<NWG, 512, 0, stream>>>(xb, qw, qz, sc, bias, out);
  } else {
    fallback_fused<<<dim3(N_OUT / 256, M_TOK), 256, 0, stream>>>(x, qw, qz, sc, bias, out);
  }
}